// Round 4
// baseline (273.884 us; speedup 1.0000x reference)
//
#include <hip/hip_runtime.h>

#define B_   8
#define S_   4096
#define D_   1024
#define M_   (B_ * S_)   // 32768 rows
#define N_   (2 * D_)    // 2048 cols (hidden | gate)
#define K_   D_          // 1024
#define CCH  128         // scan chunks
#define LCH  32          // chunk length (CCH*LCH == S_)

#define BK   64
#define NT   (K_ / BK)   // 16 k-tiles

typedef __attribute__((ext_vector_type(8))) short bf16x8;
typedef __attribute__((ext_vector_type(4))) float f32x4;

__device__ __forceinline__ unsigned short f2bf(float f) {
  union { float f; unsigned u; } v; v.f = f;
  unsigned u = v.u;
  u = u + 0x7fffu + ((u >> 16) & 1u);   // RNE
  return (unsigned short)(u >> 16);
}
__device__ __forceinline__ float bf2f(unsigned short h) {
  union { unsigned u; float f; } v; v.u = ((unsigned)h) << 16;
  return v.f;
}
__device__ __forceinline__ float sigmoidf_(float x) {
  return 1.0f / (1.0f + __expf(-x));
}

#define GLL(src, dst) __builtin_amdgcn_global_load_lds(                     \
      (const __attribute__((address_space(1))) void*)(src),                 \
      (__attribute__((address_space(3))) void*)(dst), 16, 0, 0)

// ---------- fp32 -> bf16 convert (x4 vectorized, grid-stride) ----------
__global__ __launch_bounds__(256) void k_cvt(const float* __restrict__ in,
                                             unsigned short* __restrict__ out,
                                             int n4) {
  int i = blockIdx.x * 256 + threadIdx.x;
  const int stride = gridDim.x * 256;
  for (; i < n4; i += stride) {
    float4 v = reinterpret_cast<const float4*>(in)[i];
    ushort4 o;
    o.x = f2bf(v.x); o.y = f2bf(v.y); o.z = f2bf(v.z); o.w = f2bf(v.w);
    reinterpret_cast<ushort4*>(out)[i] = o;
  }
}

// ---------- bf16 GEMM: 256x256, BK=64, m201-style 4-phase/K-tile schedule ----
// Per phase: {ds_read frags || GLL next-tile chunk -> barrier -> lgkmcnt(0) ->
// setprio(1) 16xMFMA setprio(0) -> barrier}. vmcnt(0) once per K-tile (end of
// phase 3, >=2 phases after issue). XOR-swizzled LDS (blk ^= row&7), linear
// GLL dest + pre-swizzled global source (both-sides involution).
__global__ __launch_bounds__(512, 2) void k_gemm(const unsigned short* __restrict__ xb,
                                                 const unsigned short* __restrict__ wb,
                                                 unsigned short* __restrict__ Gp,
                                                 unsigned short* __restrict__ Zp) {
  // [buf0: A 32KB | B 32KB][buf1: A 32KB | B 32KB] = 128 KiB
  __shared__ unsigned short lds[65536];
  const int tid = threadIdx.x;
  int wg = blockIdx.x;
  wg = (wg & 7) * 128 + (wg >> 3);     // XCD swizzle; 1024 % 8 == 0 -> bijective
  const int bm = wg >> 3;              // 0..127
  const int bn = wg & 7;               // 0..7
  const int lane = tid & 63;
  const int wid = tid >> 6;
  const int wr = wid >> 2;             // 0..1  (128-row band)
  const int wc = wid & 3;              // 0..3  (64-col band)
  const int fr = lane & 15;
  const int hi = lane >> 4;            // 0..3
  const int f7 = fr & 7;

  // staging: srow = tid>>3 (0..63), sblk = tid&7; LDS dest linear tid*16;
  // source block pre-swizzled so LDS[row][blk] holds global block blk^(row&7)
  const int srow = tid >> 3;
  const int scol = ((tid & 7) ^ (srow & 7)) * 16;
  const char* aS = (const char*)xb + (size_t)(bm * 256 + srow) * 2048 + scol;
  const char* bS = (const char*)wb + (size_t)(bn * 256 + srow) * 2048 + scol;
  char* const ldsc = (char*)lds + (size_t)tid * 16;

  const int swz0 = (hi ^ f7) * 8;          // kk=0 element offset within row
  const int swz1 = ((4 + hi) ^ f7) * 8;    // kk=1

  f32x4 acc[8][4] = {};
  bf16x8 av[4], bv[4];

#define RD_BV(SWZ)                                                           \
  _Pragma("unroll") for (int n = 0; n < 4; ++n)                              \
    bv[n] = *(const bf16x8*)&Bb[(wc * 64 + n * 16 + fr) * 64 + (SWZ)];
#define RD_AV(MB, SWZ)                                                       \
  _Pragma("unroll") for (int m = 0; m < 4; ++m)                              \
    av[m] = *(const bf16x8*)&Ab[(wr * 128 + (MB) * 64 + m * 16 + fr) * 64 + (SWZ)];

#define STAGE4(srcbase, region)                                              \
  if (st) {                                                                  \
    GLL((srcbase) + kb,                  ldsc + bufN + (region));            \
    GLL((srcbase) + 131072 + kb,         ldsc + bufN + (region) + 8192);     \
    GLL((srcbase) + 262144 + kb,         ldsc + bufN + (region) + 16384);    \
    GLL((srcbase) + 393216 + kb,         ldsc + bufN + (region) + 24576);    \
  }

#define PHASE16(M0)                                                          \
  __builtin_amdgcn_s_barrier();                                              \
  asm volatile("s_waitcnt lgkmcnt(0)" ::: "memory");                         \
  __builtin_amdgcn_s_setprio(1);                                             \
  _Pragma("unroll") for (int m = 0; m < 4; ++m)                              \
    _Pragma("unroll") for (int n = 0; n < 4; ++n)                            \
      acc[(M0) + m][n] = __builtin_amdgcn_mfma_f32_16x16x32_bf16(            \
          av[m], bv[n], acc[(M0) + m][n], 0, 0, 0);                          \
  __builtin_amdgcn_s_setprio(0);

  // prologue: stage tile 0 into buf0, full drain (one-time)
#pragma unroll
  for (int c = 0; c < 4; ++c) {
    GLL(aS + (size_t)c * 131072, ldsc + c * 8192);
    GLL(bS + (size_t)c * 131072, ldsc + 32768 + c * 8192);
  }
  asm volatile("s_waitcnt vmcnt(0)" ::: "memory");
  __builtin_amdgcn_s_barrier();

  for (int t = 0; t < NT; ++t) {
    const unsigned short* Ab = &lds[(t & 1) << 15];
    const unsigned short* Bb = Ab + 16384;
    const int bufN = ((t + 1) & 1) << 16;      // staging dest byte (other buf)
    const size_t kb = (size_t)(t + 1) * 128;   // next tile's k byte offset
    const bool st = (t < NT - 1);

    // phase 0: bv kk0 + av m0-3 kk0 ; stage A chunks ; MFMA m0-3 kk0
    RD_BV(swz0);
    RD_AV(0, swz0);
    STAGE4(aS, 0);
    PHASE16(0);
    __builtin_amdgcn_s_barrier();

    // phase 1: av m4-7 kk0 (bv reused) ; stage B chunks ; MFMA m4-7 kk0
    RD_AV(1, swz0);
    STAGE4(bS, 32768);
    PHASE16(4);
    __builtin_amdgcn_s_barrier();

    // phase 2: bv kk1 + av m0-3 kk1 ; MFMA m0-3 kk1
    RD_BV(swz1);
    RD_AV(0, swz1);
    PHASE16(0);
    __builtin_amdgcn_s_barrier();

    // phase 3: av m4-7 kk1 ; MFMA m4-7 kk1 ; vmcnt drain for next tile
    RD_AV(1, swz1);
    PHASE16(4);
    asm volatile("s_waitcnt vmcnt(0)" ::: "memory");
    __builtin_amdgcn_s_barrier();
  }

  // epilogue: C/D layout col = lane&15, row = (lane>>4)*4 + reg  [m89-verified]
  const int row0 = bm * 256 + wr * 128 + (hi << 2);
  const int col0 = bn * 256 + wc * 64 + fr;
  if (bn < 4) {  // hidden half -> g(hidden)
#pragma unroll
    for (int m = 0; m < 8; ++m)
#pragma unroll
      for (int n = 0; n < 4; ++n)
#pragma unroll
        for (int i = 0; i < 4; ++i) {
          float v = acc[m][n][i];
          float g = (v >= 0.0f) ? (v + 0.5f) : sigmoidf_(v);
          Gp[(size_t)(row0 + m * 16 + i) * 1024 + (col0 + n * 16)] = f2bf(g);
        }
  } else {       // gate half -> z = sigmoid(gate)
#pragma unroll
    for (int m = 0; m < 8; ++m)
#pragma unroll
      for (int n = 0; n < 4; ++n)
#pragma unroll
        for (int i = 0; i < 4; ++i) {
          float v = acc[m][n][i];
          Zp[(size_t)(row0 + m * 16 + i) * 1024 + (col0 + n * 16 - 1024)] = f2bf(sigmoidf_(v));
        }
  }
}

// ---------- scan phase 1: per-chunk local scan (h from 0) + a-product ----------
__global__ __launch_bounds__(256) void k_scan1(const unsigned short* __restrict__ Gp,
                                               const unsigned short* __restrict__ Zp,
                                               float* __restrict__ Ap,
                                               float* __restrict__ Hp) {
  const int gid = blockIdx.x * 256 + threadIdx.x;   // 0..2047
  const int c = blockIdx.y;
  const int b = gid >> 8;
  const int d0 = (gid & 255) << 2;
  size_t base = ((size_t)b * S_ + (size_t)c * LCH) * 1024 + d0;
  float4 aP = {1.f, 1.f, 1.f, 1.f};
  float4 h  = {0.f, 0.f, 0.f, 0.f};
#pragma unroll 8
  for (int s = 0; s < LCH; ++s) {
    ushort4 zu = *reinterpret_cast<const ushort4*>(Zp + base);
    ushort4 gu = *reinterpret_cast<const ushort4*>(Gp + base);
    float z0 = bf2f(zu.x), z1 = bf2f(zu.y), z2 = bf2f(zu.z), z3 = bf2f(zu.w);
    float a0 = 1.f - z0,   a1 = 1.f - z1,   a2 = 1.f - z2,   a3 = 1.f - z3;
    h.x = fmaf(a0, h.x, z0 * bf2f(gu.x));
    h.y = fmaf(a1, h.y, z1 * bf2f(gu.y));
    h.z = fmaf(a2, h.z, z2 * bf2f(gu.z));
    h.w = fmaf(a3, h.w, z3 * bf2f(gu.w));
    aP.x *= a0; aP.y *= a1; aP.z *= a2; aP.w *= a3;
    base += 1024;
  }
  reinterpret_cast<float4*>(Ap)[(size_t)c * 2048 + gid] = aP;
  reinterpret_cast<float4*>(Hp)[(size_t)c * 2048 + gid] = h;
}

// ---------- scan phase 2: sequential carry over chunks ----------
__global__ __launch_bounds__(256) void k_scan2(const float* __restrict__ Ap,
                                               const float* __restrict__ Hp,
                                               float* __restrict__ Cin) {
  const int gid = blockIdx.x * 256 + threadIdx.x;   // 0..2047
  float4 carry = {0.f, 0.f, 0.f, 0.f};
  for (int c = 0; c < CCH; ++c) {
    reinterpret_cast<float4*>(Cin)[(size_t)c * 2048 + gid] = carry;
    float4 a = reinterpret_cast<const float4*>(Ap)[(size_t)c * 2048 + gid];
    float4 hh = reinterpret_cast<const float4*>(Hp)[(size_t)c * 2048 + gid];
    carry.x = fmaf(a.x, carry.x, hh.x);
    carry.y = fmaf(a.y, carry.y, hh.y);
    carry.z = fmaf(a.z, carry.z, hh.z);
    carry.w = fmaf(a.w, carry.w, hh.w);
  }
}

// ---------- scan phase 3: replay with carry, write fp32 out ----------
__global__ __launch_bounds__(256) void k_scan3(const unsigned short* __restrict__ Gp,
                                               const unsigned short* __restrict__ Zp,
                                               const float* __restrict__ Cin,
                                               float* __restrict__ out) {
  const int gid = blockIdx.x * 256 + threadIdx.x;
  const int c = blockIdx.y;
  const int b = gid >> 8;
  const int d0 = (gid & 255) << 2;
  size_t base = ((size_t)b * S_ + (size_t)c * LCH) * 1024 + d0;
  float4 h = reinterpret_cast<const float4*>(Cin)[(size_t)c * 2048 + gid];
#pragma unroll 8
  for (int s = 0; s < LCH; ++s) {
    ushort4 zu = *reinterpret_cast<const ushort4*>(Zp + base);
    ushort4 gu = *reinterpret_cast<const ushort4*>(Gp + base);
    float z0 = bf2f(zu.x), z1 = bf2f(zu.y), z2 = bf2f(zu.z), z3 = bf2f(zu.w);
    h.x = fmaf(1.f - z0, h.x, z0 * bf2f(gu.x));
    h.y = fmaf(1.f - z1, h.y, z1 * bf2f(gu.y));
    h.z = fmaf(1.f - z2, h.z, z2 * bf2f(gu.z));
    h.w = fmaf(1.f - z3, h.w, z3 * bf2f(gu.w));
    *reinterpret_cast<float4*>(out + base) = h;
    base += 1024;
  }
}

extern "C" void kernel_launch(void* const* d_in, const int* in_sizes, int n_in,
                              void* d_out, int out_size, void* d_ws, size_t ws_size,
                              hipStream_t stream) {
  const float* x = (const float*)d_in[0];   // [8,4096,1024] f32
  const float* W = (const float*)d_in[1];   // [2048,1024]  f32
  float* out = (float*)d_out;               // [8,4096,1024] f32

  unsigned char* w = (unsigned char*)d_ws;
  // layout: xb(64MB) | wb(4MB) | Gp(64MB) | Zp(64MB). Ap/Hp/Cin alias xb
  // (xb is dead after k_gemm; 3 x 4MB << 64MB).
  unsigned short* xb = (unsigned short*)(w);
  unsigned short* wb = (unsigned short*)(w + 67108864);
  unsigned short* Gp = (unsigned short*)(w + 67108864 + 4194304);
  unsigned short* Zp = (unsigned short*)(w + 67108864 + 4194304 + 67108864);
  float* Ap  = (float*)(w);
  float* Hp  = (float*)(w + 4194304);
  float* Cin = (float*)(w + 8388608);

  k_cvt<<<4096, 256, 0, stream>>>(x, xb, (M_ * K_) / 4);
  k_cvt<<<2048, 256, 0, stream>>>(W, wb, (N_ * K_) / 4);
  k_gemm<<<(M_ / 256) * (N_ / 256), 512, 0, stream>>>(xb, wb, Gp, Zp);
  k_scan1<<<dim3(8, CCH), 256, 0, stream>>>(Gp, Zp, Ap, Hp);
  k_scan2<<<8, 256, 0, stream>>>(Ap, Hp, Cin);
  k_scan3<<<dim3(8, CCH), 256, 0, stream>>>(Gp, Zp, Cin, out);
}

// Round 5
// 270.270 us; speedup vs baseline: 1.0134x; 1.0134x over previous
//
#include <hip/hip_runtime.h>

#define B_   8
#define S_   4096
#define D_   1024
#define M_   (B_ * S_)   // 32768 rows
#define N_   (2 * D_)    // 2048 cols (hidden | gate)
#define K_   D_          // 1024
#define CCH  128         // scan chunks
#define LCH  32          // chunk length (CCH*LCH == S_)

#define BK   64
#define NT   (K_ / BK)   // 16 k-tiles

typedef __attribute__((ext_vector_type(8))) short bf16x8;
typedef __attribute__((ext_vector_type(4))) float f32x4;

__device__ __forceinline__ unsigned short f2bf(float f) {
  union { float f; unsigned u; } v; v.f = f;
  unsigned u = v.u;
  u = u + 0x7fffu + ((u >> 16) & 1u);   // RNE
  return (unsigned short)(u >> 16);
}
__device__ __forceinline__ float bf2f(unsigned short h) {
  union { unsigned u; float f; } v; v.u = ((unsigned)h) << 16;
  return v.f;
}
__device__ __forceinline__ float sigmoidf_(float x) {
  return 1.0f / (1.0f + __expf(-x));
}

#define GLL(src, dst) __builtin_amdgcn_global_load_lds(                     \
      (const __attribute__((address_space(1))) void*)(src),                 \
      (__attribute__((address_space(3))) void*)(dst), 16, 0, 0)

// ---------- fp32 -> bf16 convert (x4 vectorized, grid-stride) ----------
__global__ __launch_bounds__(256) void k_cvt(const float* __restrict__ in,
                                             unsigned short* __restrict__ out,
                                             int n4) {
  int i = blockIdx.x * 256 + threadIdx.x;
  const int stride = gridDim.x * 256;
  for (; i < n4; i += stride) {
    float4 v = reinterpret_cast<const float4*>(in)[i];
    ushort4 o;
    o.x = f2bf(v.x); o.y = f2bf(v.y); o.z = f2bf(v.z); o.w = f2bf(v.w);
    reinterpret_cast<ushort4*>(out)[i] = o;
  }
}

// ---------- bf16 GEMM: 256x256, BK=64, frag-double-buffered cluster pipeline --
// 4 MFMA clusters per K-tile; during cluster Ck the wave ISSUES ds_reads for
// C(k+1) into the alternate frag set and runs Ck's MFMAs on resident frags.
// No explicit lgkmcnt: compiler's dependence-counted waits give LDS||MFMA
// overlap. Sync: b1 = vmcnt(0)+barrier mid-C3 (next-buf GLL writes landed);
// b2 = tile-end barrier (all buf-p reads consumed before t+1 GLLs overwrite).
// XOR-swizzled LDS (blk ^= row&7), linear GLL dest + pre-swizzled source.
__global__ __launch_bounds__(512, 2) void k_gemm(const unsigned short* __restrict__ xb,
                                                 const unsigned short* __restrict__ wb,
                                                 unsigned short* __restrict__ Gp,
                                                 unsigned short* __restrict__ Zp) {
  // [buf0: A 32KB | B 32KB][buf1: A 32KB | B 32KB] = 128 KiB
  __shared__ unsigned short lds[65536];
  const int tid = threadIdx.x;
  int wg = blockIdx.x;
  wg = (wg & 7) * 128 + (wg >> 3);     // XCD swizzle; 1024 % 8 == 0 -> bijective
  const int bm = wg >> 3;              // 0..127
  const int bn = wg & 7;               // 0..7
  const int lane = tid & 63;
  const int wid = tid >> 6;
  const int wr = wid >> 2;             // 0..1  (128-row band)
  const int wc = wid & 3;              // 0..3  (64-col band)
  const int fr = lane & 15;
  const int hi = lane >> 4;            // 0..3
  const int f7 = fr & 7;

  // staging: srow = tid>>3 (0..63), sblk = tid&7; LDS dest linear tid*16;
  // source block pre-swizzled so LDS[row][blk] holds global block blk^(row&7)
  const int srow = tid >> 3;
  const int scol = ((tid & 7) ^ (srow & 7)) * 16;
  const char* aS = (const char*)xb + (size_t)(bm * 256 + srow) * 2048 + scol;
  const char* bS = (const char*)wb + (size_t)(bn * 256 + srow) * 2048 + scol;
  char* const ldsc = (char*)lds + (size_t)tid * 16;   // per-thread stage dest
  const char* const ldsr = (const char*)lds;          // read base

  // frag read addressing (bytes): row*128 + swz*16
  const int aoff = (wr * 128 + fr) * 128;
  const int boff = (wc * 64 + fr) * 128;
  const int s0 = (hi ^ f7) * 16;          // kk=0 swizzled byte offset
  const int s1 = ((4 + hi) ^ f7) * 16;    // kk=1

  f32x4 acc[8][4] = {};
  bf16x8 avA[4], avB[4], bvA[4], bvB[4];

#define MM16(AV, BV, O)                                                      \
  __builtin_amdgcn_s_setprio(1);                                             \
  _Pragma("unroll") for (int m = 0; m < 4; ++m)                              \
    _Pragma("unroll") for (int n = 0; n < 4; ++n)                            \
      acc[(O) + m][n] = __builtin_amdgcn_mfma_f32_16x16x32_bf16(             \
          AV[m], BV[n], acc[(O) + m][n], 0, 0, 0);                           \
  __builtin_amdgcn_s_setprio(0);

  // prologue: stage tile 0 -> buf0, drain, preload C0 frags (kk0: avA, bvA)
#pragma unroll
  for (int c = 0; c < 4; ++c) {
    GLL(aS + (size_t)c * 131072, ldsc + c * 8192);
    GLL(bS + (size_t)c * 131072, ldsc + 32768 + c * 8192);
  }
  asm volatile("s_waitcnt vmcnt(0)\n\ts_barrier" ::: "memory");
#pragma unroll
  for (int m = 0; m < 4; ++m)
    avA[m] = *(const bf16x8*)(ldsr + aoff + m * 2048 + s0);
#pragma unroll
  for (int n = 0; n < 4; ++n)
    bvA[n] = *(const bf16x8*)(ldsr + 32768 + boff + n * 2048 + s0);

  for (int t = 0; t < NT; ++t) {
    const bool st = (t < NT - 1);
    const char* Ab = ldsr + ((t & 1) << 16);         // current buf A (bytes)
    const char* Bb = Ab + 32768;                     // current buf B
    const char* An = ldsr + (((t + 1) & 1) << 16);   // next buf A
    const char* Bn = An + 32768;
    char* dq = ldsc + (((t + 1) & 1) << 16);         // stage dest (next buf)
    const size_t kb = (size_t)(t + 1) * 128;

    // ---- C0: GLL A-chunks(t+1) ; read avB=kk0,m4-7 ; MFMA(avA,bvA)->acc0-3
    if (st) {
      GLL(aS + kb, dq);                    GLL(aS + 131072 + kb, dq + 8192);
      GLL(aS + 262144 + kb, dq + 16384);   GLL(aS + 393216 + kb, dq + 24576);
    }
#pragma unroll
    for (int m = 0; m < 4; ++m)
      avB[m] = *(const bf16x8*)(Ab + aoff + (4 + m) * 2048 + s0);
    MM16(avA, bvA, 0);

    // ---- C1: GLL B-chunks(t+1) ; read avA=kk1,m0-3 + bvB=kk1 ; MFMA(avB,bvA)
    if (st) {
      GLL(bS + kb, dq + 32768);            GLL(bS + 131072 + kb, dq + 40960);
      GLL(bS + 262144 + kb, dq + 49152);   GLL(bS + 393216 + kb, dq + 57344);
    }
#pragma unroll
    for (int m = 0; m < 4; ++m)
      avA[m] = *(const bf16x8*)(Ab + aoff + m * 2048 + s1);
#pragma unroll
    for (int n = 0; n < 4; ++n)
      bvB[n] = *(const bf16x8*)(Bb + boff + n * 2048 + s1);
    MM16(avB, bvA, 4);

    // ---- C2: read avB=kk1,m4-7 ; MFMA(avA,bvB)->acc0-3
#pragma unroll
    for (int m = 0; m < 4; ++m)
      avB[m] = *(const bf16x8*)(Ab + aoff + (4 + m) * 2048 + s1);
    MM16(avA, bvB, 0);

    // ---- C3: b1 (GLLs to next buf landed CU-wide) ; read t+1 C0 frags ;
    //          MFMA(avB,bvB)->acc4-7 ; b2 tile-end barrier
    asm volatile("s_waitcnt vmcnt(0)\n\ts_barrier" ::: "memory");
    if (st) {
#pragma unroll
      for (int m = 0; m < 4; ++m)
        avA[m] = *(const bf16x8*)(An + aoff + m * 2048 + s0);
#pragma unroll
      for (int n = 0; n < 4; ++n)
        bvA[n] = *(const bf16x8*)(Bn + boff + n * 2048 + s0);
    }
    MM16(avB, bvB, 4);
    __builtin_amdgcn_s_barrier();
  }

  // epilogue: C/D layout col = lane&15, row = (lane>>4)*4 + reg  [m89-verified]
  const int row0 = bm * 256 + wr * 128 + (hi << 2);
  const int col0 = bn * 256 + wc * 64 + fr;
  if (bn < 4) {  // hidden half -> g(hidden)
#pragma unroll
    for (int m = 0; m < 8; ++m)
#pragma unroll
      for (int n = 0; n < 4; ++n)
#pragma unroll
        for (int i = 0; i < 4; ++i) {
          float v = acc[m][n][i];
          float g = (v >= 0.0f) ? (v + 0.5f) : sigmoidf_(v);
          Gp[(size_t)(row0 + m * 16 + i) * 1024 + (col0 + n * 16)] = f2bf(g);
        }
  } else {       // gate half -> z = sigmoid(gate)
#pragma unroll
    for (int m = 0; m < 8; ++m)
#pragma unroll
      for (int n = 0; n < 4; ++n)
#pragma unroll
        for (int i = 0; i < 4; ++i) {
          float v = acc[m][n][i];
          Zp[(size_t)(row0 + m * 16 + i) * 1024 + (col0 + n * 16 - 1024)] = f2bf(sigmoidf_(v));
        }
  }
}

// ---------- scan phase 1: per-chunk local scan (h from 0) + a-product ----------
__global__ __launch_bounds__(256) void k_scan1(const unsigned short* __restrict__ Gp,
                                               const unsigned short* __restrict__ Zp,
                                               float* __restrict__ Ap,
                                               float* __restrict__ Hp) {
  const int gid = blockIdx.x * 256 + threadIdx.x;   // 0..2047
  const int c = blockIdx.y;
  const int b = gid >> 8;
  const int d0 = (gid & 255) << 2;
  size_t base = ((size_t)b * S_ + (size_t)c * LCH) * 1024 + d0;
  float4 aP = {1.f, 1.f, 1.f, 1.f};
  float4 h  = {0.f, 0.f, 0.f, 0.f};
#pragma unroll 8
  for (int s = 0; s < LCH; ++s) {
    ushort4 zu = *reinterpret_cast<const ushort4*>(Zp + base);
    ushort4 gu = *reinterpret_cast<const ushort4*>(Gp + base);
    float z0 = bf2f(zu.x), z1 = bf2f(zu.y), z2 = bf2f(zu.z), z3 = bf2f(zu.w);
    float a0 = 1.f - z0,   a1 = 1.f - z1,   a2 = 1.f - z2,   a3 = 1.f - z3;
    h.x = fmaf(a0, h.x, z0 * bf2f(gu.x));
    h.y = fmaf(a1, h.y, z1 * bf2f(gu.y));
    h.z = fmaf(a2, h.z, z2 * bf2f(gu.z));
    h.w = fmaf(a3, h.w, z3 * bf2f(gu.w));
    aP.x *= a0; aP.y *= a1; aP.z *= a2; aP.w *= a3;
    base += 1024;
  }
  reinterpret_cast<float4*>(Ap)[(size_t)c * 2048 + gid] = aP;
  reinterpret_cast<float4*>(Hp)[(size_t)c * 2048 + gid] = h;
}

// ---------- scan phase 2: sequential carry over chunks ----------
__global__ __launch_bounds__(256) void k_scan2(const float* __restrict__ Ap,
                                               const float* __restrict__ Hp,
                                               float* __restrict__ Cin) {
  const int gid = blockIdx.x * 256 + threadIdx.x;   // 0..2047
  float4 carry = {0.f, 0.f, 0.f, 0.f};
  for (int c = 0; c < CCH; ++c) {
    reinterpret_cast<float4*>(Cin)[(size_t)c * 2048 + gid] = carry;
    float4 a = reinterpret_cast<const float4*>(Ap)[(size_t)c * 2048 + gid];
    float4 hh = reinterpret_cast<const float4*>(Hp)[(size_t)c * 2048 + gid];
    carry.x = fmaf(a.x, carry.x, hh.x);
    carry.y = fmaf(a.y, carry.y, hh.y);
    carry.z = fmaf(a.z, carry.z, hh.z);
    carry.w = fmaf(a.w, carry.w, hh.w);
  }
}

// ---------- scan phase 3: replay with carry, write fp32 out ----------
__global__ __launch_bounds__(256) void k_scan3(const unsigned short* __restrict__ Gp,
                                               const unsigned short* __restrict__ Zp,
                                               const float* __restrict__ Cin,
                                               float* __restrict__ out) {
  const int gid = blockIdx.x * 256 + threadIdx.x;
  const int c = blockIdx.y;
  const int b = gid >> 8;
  const int d0 = (gid & 255) << 2;
  size_t base = ((size_t)b * S_ + (size_t)c * LCH) * 1024 + d0;
  float4 h = reinterpret_cast<const float4*>(Cin)[(size_t)c * 2048 + gid];
#pragma unroll 8
  for (int s = 0; s < LCH; ++s) {
    ushort4 zu = *reinterpret_cast<const ushort4*>(Zp + base);
    ushort4 gu = *reinterpret_cast<const ushort4*>(Gp + base);
    float z0 = bf2f(zu.x), z1 = bf2f(zu.y), z2 = bf2f(zu.z), z3 = bf2f(zu.w);
    h.x = fmaf(1.f - z0, h.x, z0 * bf2f(gu.x));
    h.y = fmaf(1.f - z1, h.y, z1 * bf2f(gu.y));
    h.z = fmaf(1.f - z2, h.z, z2 * bf2f(gu.z));
    h.w = fmaf(1.f - z3, h.w, z3 * bf2f(gu.w));
    *reinterpret_cast<float4*>(out + base) = h;
    base += 1024;
  }
}

extern "C" void kernel_launch(void* const* d_in, const int* in_sizes, int n_in,
                              void* d_out, int out_size, void* d_ws, size_t ws_size,
                              hipStream_t stream) {
  const float* x = (const float*)d_in[0];   // [8,4096,1024] f32
  const float* W = (const float*)d_in[1];   // [2048,1024]  f32
  float* out = (float*)d_out;               // [8,4096,1024] f32

  unsigned char* w = (unsigned char*)d_ws;
  // layout: xb(64MB) | wb(4MB) | Gp(64MB) | Zp(64MB). Ap/Hp/Cin alias xb
  // (xb is dead after k_gemm; 3 x 4MB << 64MB).
  unsigned short* xb = (unsigned short*)(w);
  unsigned short* wb = (unsigned short*)(w + 67108864);
  unsigned short* Gp = (unsigned short*)(w + 67108864 + 4194304);
  unsigned short* Zp = (unsigned short*)(w + 67108864 + 4194304 + 67108864);
  float* Ap  = (float*)(w);
  float* Hp  = (float*)(w + 4194304);
  float* Cin = (float*)(w + 8388608);

  k_cvt<<<4096, 256, 0, stream>>>(x, xb, (M_ * K_) / 4);
  k_cvt<<<2048, 256, 0, stream>>>(W, wb, (N_ * K_) / 4);
  k_gemm<<<(M_ / 256) * (N_ / 256), 512, 0, stream>>>(xb, wb, Gp, Zp);
  k_scan1<<<dim3(8, CCH), 256, 0, stream>>>(Gp, Zp, Ap, Hp);
  k_scan2<<<8, 256, 0, stream>>>(Ap, Hp, Cin);
  k_scan3<<<dim3(8, CCH), 256, 0, stream>>>(Gp, Zp, Cin, out);
}